// Round 4
// baseline (469.147 us; speedup 1.0000x reference)
//
#include <hip/hip_runtime.h>
#include <hip/hip_bf16.h>

// ---------------- problem constants (match setup_inputs) ----------------
#define T_TOK 4096
#define H_DIM 1024
#define E_NUM 8
#define I_DIM 3584
#define NPAIR (T_TOK * 2)   // top_k = 2

#define BM 256
#define BN 128
#define BK 64
#define MAX_RT 39           // worst case: sum_e ceil(cnt_e/256) <= 32 + 7
#define KSPLIT 1792         // MODE1 K-split segment (I_DIM/2)

typedef __attribute__((ext_vector_type(8))) short bf16x8;
typedef __attribute__((ext_vector_type(4))) float f32x4;
typedef __attribute__((ext_vector_type(8))) unsigned short ushort8_t;
typedef __attribute__((ext_vector_type(4))) unsigned short ushort4_t;

// RNE fp32 -> bf16
__device__ __forceinline__ unsigned short f2bf(float x) {
  unsigned int u = __float_as_uint(x);
  unsigned int r = (u + 0x7FFFu + ((u >> 16) & 1u)) >> 16;
  return (unsigned short)r;
}

// async 16B global -> LDS (dest: wave-uniform base, HW adds lane*16)
__device__ __forceinline__ void gload16(const void* g, unsigned short* l) {
  __builtin_amdgcn_global_load_lds(
      (const __attribute__((address_space(1))) void*)g,
      (__attribute__((address_space(3))) void*)l, 16, 0, 0);
}

// ---------------- transpose + fp32->bf16 convert ----------------
// src: [E][R][C] fp32 -> dst: [E][C][R] bf16.  grid (C/64, R/64, E), 256 thr
__global__ void transpose_cvt(const float* __restrict__ src,
                              unsigned short* __restrict__ dst, int R, int C) {
  __shared__ float tile[64][65];   // stride 65: 2-way max on both passes
  const int e = blockIdx.z;
  const int c0 = blockIdx.x * 64, r0 = blockIdx.y * 64;
  const float* s = src + (size_t)e * R * C;
  unsigned short* d = dst + (size_t)e * R * C;
  const int th = threadIdx.x;
  const int tr = th >> 4;          // 0..15
  const int tc = (th & 15) * 4;    // 0..60
#pragma unroll
  for (int rr = 0; rr < 4; ++rr) {
    const int r = rr * 16 + tr;
    float4 v = *reinterpret_cast<const float4*>(s + (size_t)(r0 + r) * C + c0 + tc);
    tile[r][tc] = v.x; tile[r][tc + 1] = v.y; tile[r][tc + 2] = v.z; tile[r][tc + 3] = v.w;
  }
  __syncthreads();
#pragma unroll
  for (int rr = 0; rr < 4; ++rr) {
    const int c = rr * 16 + tr;
    ushort4_t o = { f2bf(tile[tc][c]), f2bf(tile[tc + 1][c]),
                    f2bf(tile[tc + 2][c]), f2bf(tile[tc + 3][c]) };
    *reinterpret_cast<ushort4_t*>(d + (size_t)(c0 + c) * R + r0 + tc) = o;
  }
}

// ---------------- router (one wave per token) + hs->bf16 conversion --------
__global__ void router_kernel(const float* __restrict__ hs, const float* __restrict__ gw,
                              unsigned short* __restrict__ hsb,
                              int* __restrict__ eid, float* __restrict__ wgt,
                              int* __restrict__ counts) {
  const int th = threadIdx.x;
  const int l = th & 63;
  const int t = blockIdx.x * 4 + (th >> 6);
  float acc[E_NUM];
#pragma unroll
  for (int e = 0; e < E_NUM; ++e) acc[e] = 0.f;
  const float* hrow = hs + (size_t)t * H_DIM;
  unsigned short* brow = hsb + (size_t)t * H_DIM;
  for (int h = l; h < H_DIM; h += 64) {
    const float x = hrow[h];
    brow[h] = f2bf(x);
    float4 g0 = *reinterpret_cast<const float4*>(gw + h * E_NUM);
    float4 g1 = *reinterpret_cast<const float4*>(gw + h * E_NUM + 4);
    acc[0] += x * g0.x; acc[1] += x * g0.y; acc[2] += x * g0.z; acc[3] += x * g0.w;
    acc[4] += x * g1.x; acc[5] += x * g1.y; acc[6] += x * g1.z; acc[7] += x * g1.w;
  }
#pragma unroll
  for (int e = 0; e < E_NUM; ++e) {
#pragma unroll
    for (int off = 32; off > 0; off >>= 1) acc[e] += __shfl_down(acc[e], off);
  }
  if (l == 0) {
    int i1 = 0;
#pragma unroll
    for (int e = 1; e < E_NUM; ++e) if (acc[e] > acc[i1]) i1 = e;
    int i2 = (i1 == 0) ? 1 : 0;
#pragma unroll
    for (int e = 0; e < E_NUM; ++e) if (e != i1 && acc[e] > acc[i2]) i2 = e;
    const float e2 = __expf(acc[i2] - acc[i1]);
    const float inv = 1.f / (1.f + e2);
    eid[t * 2] = i1;     wgt[t * 2] = inv;
    eid[t * 2 + 1] = i2; wgt[t * 2 + 1] = e2 * inv;
    atomicAdd(&counts[i1], 1);
    atomicAdd(&counts[i2], 1);
  }
}

__global__ void scatter_kernel(const int* __restrict__ eid, const int* __restrict__ counts,
                               int* __restrict__ fill, int* __restrict__ rowmap) {
  const int p = blockIdx.x * blockDim.x + threadIdx.x;
  if (p < NPAIR) {
    const int e = eid[p];
    int off = 0;
#pragma unroll
    for (int i = 0; i < E_NUM; ++i) off += (i < e) ? counts[i] : 0;
    const int pos = atomicAdd(&fill[e], 1);
    rowmap[off + pos] = p;
  }
}

// ---------------- grouped GEMM: 256x128 tile, 3-ring LDS, counted vmcnt ----
// MODE 0: A = gathered hs bf16 [K=1024], B = w1t [E][I][H], C = silu -> act
// MODE 1: A = act bf16 [K-split 1792], B = w2t [E][H][I], C -> atomicAdd out
template <int MODE>
__launch_bounds__(512, 2)
__global__ void moe_gemm(const unsigned short* __restrict__ hsb,
                         const unsigned short* __restrict__ wt,
                         const unsigned short* __restrict__ act_in,
                         unsigned short* __restrict__ act_out,
                         float* __restrict__ out,
                         const int* __restrict__ counts,
                         const int* __restrict__ rowmap,
                         const float* __restrict__ wgt) {
  constexpr int KBS = (MODE == 0) ? H_DIM : I_DIM;     // B row stride
  constexpr int NT  = (MODE == 0) ? (H_DIM / BK) : (KSPLIT / BK);  // 16 / 28
  constexpr int AR = BM * BK;      // 16384 shorts per A ring
  constexpr int BR = BN * BK;      // 8192 shorts per B ring
  constexpr int BOFF = 3 * AR;     // B rings base

  __shared__ unsigned short S[3 * AR + 3 * BR];   // 144 KB
  __shared__ int s_pair[BM];
  __shared__ float s_w[BM];

  // grid decode: bid = (ks*NCT + ct)*MAX_RT + rt  (rt fast: B panel shared)
  const int bid = blockIdx.x;
  const int rt = bid % MAX_RT;
  int ct, kbase;
  if (MODE == 0) { ct = bid / MAX_RT; kbase = 0; }
  else { const int q = bid / MAX_RT; ct = q & 7; kbase = (q >> 3) * KSPLIT; }

  // expert walk from counts (prefix on the fly)
  int e = -1, loc_rt = 0, off_e = 0, cnt = 0;
  {
    int acc_t = 0, off = 0;
#pragma unroll
    for (int ee = 0; ee < E_NUM; ++ee) {
      const int c = counts[ee];
      const int nt = (c + BM - 1) >> 8;
      if (e < 0 && rt < acc_t + nt) { e = ee; loc_rt = rt - acc_t; off_e = off; cnt = c; }
      acc_t += nt; off += c;
    }
  }
  if (e < 0) return;

  const int cnt_local = min(BM, cnt - loc_rt * BM);
  const int r_base = off_e + loc_rt * BM;
  const int th = threadIdx.x;
  const int lane = th & 63, wid = th >> 6;

  if (MODE == 1 && th < BM) {
    int r = loc_rt * BM + th;
    if (r >= cnt) r = cnt - 1;
    const int p = rowmap[off_e + r];
    s_pair[th] = p;
    s_w[th] = wgt[p];
  }

  const int n0 = ct * BN;
  const unsigned short* wbase = wt + (size_t)e * ((size_t)I_DIM * H_DIM) + (size_t)n0 * KBS;

  // staging: thread covers (row = i*64 + th/8, chunk = th%8), source pre-swizzled
  const int srow = th >> 3;                 // 0..63
  const int cg = (th & 7) ^ (srow & 7);
  const char* aptr[4];
  const char* bptr[2];
#pragma unroll
  for (int i = 0; i < 4; ++i) {
    const int r = i * 64 + srow;
    const int rr = (r < cnt_local) ? r : (cnt_local - 1);
    if (MODE == 0) {
      const int tok = rowmap[off_e + loc_rt * BM + rr] >> 1;
      aptr[i] = (const char*)(hsb + (size_t)tok * H_DIM) + cg * 16;
    } else {
      aptr[i] = (const char*)(act_in + (size_t)(r_base + rr) * I_DIM + kbase) + cg * 16;
    }
  }
#pragma unroll
  for (int j = 0; j < 2; ++j) {
    const int r = j * 64 + srow;
    bptr[j] = (const char*)(wbase + (size_t)r * KBS + kbase) + cg * 16;
  }

#define STG_H0(w, kb) do {                                        \
    gload16(aptr[0] + (kb), &S[(w)*AR + (wid * 8) * 64]);         \
    gload16(aptr[1] + (kb), &S[(w)*AR + (64 + wid * 8) * 64]);    \
    gload16(bptr[0] + (kb), &S[BOFF + (w)*BR + (wid * 8) * 64]);  \
  } while (0)
#define STG_H1(w, kb) do {                                        \
    gload16(aptr[2] + (kb), &S[(w)*AR + (128 + wid * 8) * 64]);   \
    gload16(aptr[3] + (kb), &S[(w)*AR + (192 + wid * 8) * 64]);   \
    gload16(bptr[1] + (kb), &S[BOFF + (w)*BR + (64 + wid * 8) * 64]); \
  } while (0)

  // wave tiling: 4M x 2N waves, 64x64 per wave
  const int wr = wid >> 1, wc = wid & 1;
  const int fr = lane & 15, fq = lane >> 4;
  const int sx = fr & 7;
  const int ck0 = (fq ^ sx) * 8;
  const int ck1 = ((4 + fq) ^ sx) * 8;
  const int arow = (wr * 64 + fr) * 64;     // + mi*16*64
  const int brow = (wc * 64 + fr) * 64;     // + (nh*32 + ni*16)*64

  f32x4 acc[4][4];
#pragma unroll
  for (int mi = 0; mi < 4; ++mi)
#pragma unroll
    for (int nj = 0; nj < 4; ++nj) acc[mi][nj] = (f32x4){0.f, 0.f, 0.f, 0.f};

  // prologue: K-tile 0 -> ring0, K-tile 1 -> ring1; wait K0 (6 newest in flight)
  STG_H0(0, 0); STG_H1(0, 0);
  STG_H0(1, 128); STG_H1(1, 128);
  asm volatile("s_waitcnt vmcnt(6)" ::: "memory");
  __builtin_amdgcn_s_barrier();

  int rd = 0, wrr = 2;
  for (int t = 0; t < NT; ++t) {
    const int kb = (t + 2) * 128;            // byte offset of K-tile t+2
    const bool stg = (t + 2) < NT;
    const unsigned short* Ab = &S[rd * AR];
    const unsigned short* Bb = &S[BOFF + rd * BR];
    bf16x8 af[4][2];
    // ---- phase 0: n-half 0 (A frags read once, held across both phases)
    {
#pragma unroll
      for (int mi = 0; mi < 4; ++mi) {
        af[mi][0] = *reinterpret_cast<const bf16x8*>(&Ab[arow + mi * 1024 + ck0]);
        af[mi][1] = *reinterpret_cast<const bf16x8*>(&Ab[arow + mi * 1024 + ck1]);
      }
      bf16x8 bf0[2][2];
#pragma unroll
      for (int ni = 0; ni < 2; ++ni) {
        bf0[ni][0] = *reinterpret_cast<const bf16x8*>(&Bb[brow + ni * 1024 + ck0]);
        bf0[ni][1] = *reinterpret_cast<const bf16x8*>(&Bb[brow + ni * 1024 + ck1]);
      }
      if (stg) STG_H0(wrr, kb);
      __builtin_amdgcn_s_barrier();
      asm volatile("s_waitcnt lgkmcnt(0)" ::: "memory");
      __builtin_amdgcn_sched_barrier(0);
      __builtin_amdgcn_s_setprio(1);
#pragma unroll
      for (int kk = 0; kk < 2; ++kk)
#pragma unroll
        for (int mi = 0; mi < 4; ++mi)
#pragma unroll
          for (int ni = 0; ni < 2; ++ni)
            acc[mi][ni] = __builtin_amdgcn_mfma_f32_16x16x32_bf16(
                af[mi][kk], bf0[ni][kk], acc[mi][ni], 0, 0, 0);
      __builtin_amdgcn_s_setprio(0);
    }
    __builtin_amdgcn_s_barrier();
    // ---- phase 1: n-half 1
    {
      bf16x8 bf1[2][2];
#pragma unroll
      for (int ni = 0; ni < 2; ++ni) {
        bf1[ni][0] = *reinterpret_cast<const bf16x8*>(&Bb[brow + 2048 + ni * 1024 + ck0]);
        bf1[ni][1] = *reinterpret_cast<const bf16x8*>(&Bb[brow + 2048 + ni * 1024 + ck1]);
      }
      if (stg) STG_H1(wrr, kb);
      __builtin_amdgcn_s_barrier();
      asm volatile("s_waitcnt lgkmcnt(0)" ::: "memory");
      __builtin_amdgcn_sched_barrier(0);
      __builtin_amdgcn_s_setprio(1);
#pragma unroll
      for (int kk = 0; kk < 2; ++kk)
#pragma unroll
        for (int mi = 0; mi < 4; ++mi)
#pragma unroll
          for (int ni = 0; ni < 2; ++ni)
            acc[mi][2 + ni] = __builtin_amdgcn_mfma_f32_16x16x32_bf16(
                af[mi][kk], bf1[ni][kk], acc[mi][2 + ni], 0, 0, 0);
      __builtin_amdgcn_s_setprio(0);
    }
    // K-tile boundary: K(t+1) landed iff only this iter's 6 stages outstanding
    if (stg) asm volatile("s_waitcnt vmcnt(6)" ::: "memory");
    else     asm volatile("s_waitcnt vmcnt(0)" ::: "memory");
    __builtin_amdgcn_sched_barrier(0);
    __builtin_amdgcn_s_barrier();
    rd = (rd == 2) ? 0 : rd + 1;
    wrr = (wrr == 2) ? 0 : wrr + 1;
  }
#undef STG_H0
#undef STG_H1

  // ---- epilogue ----
#pragma unroll
  for (int mi = 0; mi < 4; ++mi) {
    const int row = wr * 64 + mi * 16 + fq * 4;
#pragma unroll
    for (int nj = 0; nj < 4; ++nj) {
      const int col = n0 + wc * 64 + nj * 16 + fr;
#pragma unroll
      for (int r2 = 0; r2 < 4; ++r2) {
        const int rw = row + r2;
        if (rw < cnt_local) {
          const float x = acc[mi][nj][r2];
          if (MODE == 0) {
            const float s = x / (1.f + __expf(-x));   // silu
            act_out[(size_t)(r_base + rw) * I_DIM + col] = f2bf(s);
          } else {
            const int tok = s_pair[rw] >> 1;
            atomicAdd(out + (size_t)tok * H_DIM + col, x * s_w[rw]);
          }
        }
      }
    }
  }
}

// ---------------- launch ----------------
extern "C" void kernel_launch(void* const* d_in, const int* in_sizes, int n_in,
                              void* d_out, int out_size, void* d_ws, size_t ws_size,
                              hipStream_t stream) {
  const float* hs = (const float*)d_in[0];
  const float* gw = (const float*)d_in[1];
  const float* w1 = (const float*)d_in[2];
  const float* w2 = (const float*)d_in[3];
  float* out = (float*)d_out;

  char* ws = (char*)d_ws;
  const size_t WMAT = (size_t)E_NUM * I_DIM * H_DIM * 2;   // 58,720,256 B
  unsigned short* w1t = (unsigned short*)ws;                // [E][I][H] bf16
  unsigned short* w2t = (unsigned short*)(ws + WMAT);       // [E][H][I] bf16
  unsigned short* act = (unsigned short*)(ws + 2 * WMAT);   // [NPAIR][I] bf16
  unsigned short* hsb = (unsigned short*)(ws + 3 * WMAT);   // [T][H] bf16
  char* small = ws + 3 * WMAT + (size_t)T_TOK * H_DIM * 2;
  int* eid = (int*)small;                          // NPAIR
  float* wgt = (float*)(small + NPAIR * 4);        // NPAIR
  int* rowmap = (int*)(small + 2 * NPAIR * 4);     // NPAIR
  int* counts = (int*)(small + 3 * NPAIR * 4);     // 8
  int* fill = counts + 8;                          // 8

  hipMemsetAsync(d_out, 0, (size_t)T_TOK * H_DIM * sizeof(float), stream);
  hipMemsetAsync(counts, 0, 16 * sizeof(int), stream);

  transpose_cvt<<<dim3(I_DIM / 64, H_DIM / 64, E_NUM), 256, 0, stream>>>(w1, w1t, H_DIM, I_DIM);
  transpose_cvt<<<dim3(H_DIM / 64, I_DIM / 64, E_NUM), 256, 0, stream>>>(w2, w2t, I_DIM, H_DIM);

  router_kernel<<<T_TOK / 4, 256, 0, stream>>>(hs, gw, hsb, eid, wgt, counts);
  scatter_kernel<<<NPAIR / 256, 256, 0, stream>>>(eid, counts, fill, rowmap);

  moe_gemm<0><<<MAX_RT * (I_DIM / BN), 512, 0, stream>>>(
      hsb, w1t, nullptr, act, nullptr, counts, rowmap, wgt);
  moe_gemm<1><<<MAX_RT * (H_DIM / BN) * 2, 512, 0, stream>>>(
      hsb, w2t, act, nullptr, out, counts, rowmap, wgt);
}

// Round 5
// 386.255 us; speedup vs baseline: 1.2146x; 1.2146x over previous
//
#include <hip/hip_runtime.h>
#include <hip/hip_bf16.h>

// ---------------- problem constants (match setup_inputs) ----------------
#define T_TOK 4096
#define H_DIM 1024
#define E_NUM 8
#define I_DIM 3584
#define NPAIR (T_TOK * 2)   // top_k = 2
#define MAX_RT 72           // worst-case total row tiles: sum ceil(cnt_e/128) <= 64+7

#define BM 128
#define BN 128
#define BK 64

typedef __attribute__((ext_vector_type(8))) short bf16x8;
typedef __attribute__((ext_vector_type(4))) float f32x4;
typedef __attribute__((ext_vector_type(8))) unsigned short ushort8_t;
typedef __attribute__((ext_vector_type(4))) unsigned short ushort4_t;

// RNE fp32 -> bf16
__device__ __forceinline__ unsigned short f2bf(float x) {
  unsigned int u = __float_as_uint(x);
  unsigned int r = (u + 0x7FFFu + ((u >> 16) & 1u)) >> 16;
  return (unsigned short)r;
}

// async 16B global -> LDS (dest: wave-uniform base, HW adds lane*16)
__device__ __forceinline__ void gload16(const void* g, unsigned short* l) {
  __builtin_amdgcn_global_load_lds(
      (const __attribute__((address_space(1))) void*)g,
      (__attribute__((address_space(3))) void*)l, 16, 0, 0);
}

// ---------------- transpose + fp32->bf16 convert ----------------
// src: [E][R][C] fp32 -> dst: [E][C][R] bf16.  grid (C/64, R/64, E), 256 thr
// read: float4 coalesced; write: ushort8 (16B) -> 128B segments
__global__ void transpose_cvt(const float* __restrict__ src,
                              unsigned short* __restrict__ dst, int R, int C) {
  __shared__ float tile[64][65];   // stride 65 -> 2-way max on column reads
  const int e = blockIdx.z;
  const int c0 = blockIdx.x * 64, r0 = blockIdx.y * 64;
  const float* s = src + (size_t)e * R * C;
  unsigned short* d = dst + (size_t)e * R * C;
  const int th = threadIdx.x;
  const int tr = th >> 4;          // 0..15
  const int tc4 = (th & 15) * 4;   // 0..60
#pragma unroll
  for (int it = 0; it < 4; ++it) {
    const int r = it * 16 + tr;
    float4 v = *reinterpret_cast<const float4*>(s + (size_t)(r0 + r) * C + c0 + tc4);
    tile[r][tc4] = v.x; tile[r][tc4 + 1] = v.y; tile[r][tc4 + 2] = v.z; tile[r][tc4 + 3] = v.w;
  }
  __syncthreads();
  const int wc = th >> 3;          // 0..31
  const int wr = (th & 7) * 8;     // 0..56
#pragma unroll
  for (int it = 0; it < 2; ++it) {
    const int c = it * 32 + wc;
    ushort8_t o;
#pragma unroll
    for (int j = 0; j < 8; ++j) o[j] = f2bf(tile[wr + j][c]);
    *reinterpret_cast<ushort8_t*>(d + (size_t)(c0 + c) * R + r0 + wr) = o;
  }
}

// ---------------- router (one wave per token) + hs->bf16 conversion --------
__global__ void router_kernel(const float* __restrict__ hs, const float* __restrict__ gw,
                              unsigned short* __restrict__ hsb,
                              int* __restrict__ eid, float* __restrict__ wgt,
                              int* __restrict__ counts) {
  const int th = threadIdx.x;
  const int l = th & 63;
  const int t = blockIdx.x * 4 + (th >> 6);
  float acc[E_NUM];
#pragma unroll
  for (int e = 0; e < E_NUM; ++e) acc[e] = 0.f;
  const float* hrow = hs + (size_t)t * H_DIM;
  unsigned short* brow = hsb + (size_t)t * H_DIM;
  for (int h = l; h < H_DIM; h += 64) {
    const float x = hrow[h];
    brow[h] = f2bf(x);
    float4 g0 = *reinterpret_cast<const float4*>(gw + h * E_NUM);
    float4 g1 = *reinterpret_cast<const float4*>(gw + h * E_NUM + 4);
    acc[0] += x * g0.x; acc[1] += x * g0.y; acc[2] += x * g0.z; acc[3] += x * g0.w;
    acc[4] += x * g1.x; acc[5] += x * g1.y; acc[6] += x * g1.z; acc[7] += x * g1.w;
  }
#pragma unroll
  for (int e = 0; e < E_NUM; ++e) {
#pragma unroll
    for (int off = 32; off > 0; off >>= 1) acc[e] += __shfl_down(acc[e], off);
  }
  if (l == 0) {
    int i1 = 0;
#pragma unroll
    for (int e = 1; e < E_NUM; ++e) if (acc[e] > acc[i1]) i1 = e;
    int i2 = (i1 == 0) ? 1 : 0;
#pragma unroll
    for (int e = 0; e < E_NUM; ++e) if (e != i1 && acc[e] > acc[i2]) i2 = e;
    const float e2 = __expf(acc[i2] - acc[i1]);
    const float inv = 1.f / (1.f + e2);
    eid[t * 2] = i1;     wgt[t * 2] = inv;
    eid[t * 2 + 1] = i2; wgt[t * 2 + 1] = e2 * inv;
    atomicAdd(&counts[i1], 1);
    atomicAdd(&counts[i2], 1);
  }
}

// scatter: prefix from counts computed per-thread (8 ints, L2-hot)
__global__ void scatter_kernel(const int* __restrict__ eid, const int* __restrict__ counts,
                               int* __restrict__ fill, int* __restrict__ rowmap) {
  const int p = blockIdx.x * blockDim.x + threadIdx.x;
  if (p < NPAIR) {
    const int e = eid[p];
    int off = 0;
#pragma unroll
    for (int i = 0; i < E_NUM; ++i) off += (i < e) ? counts[i] : 0;
    const int pos = atomicAdd(&fill[e], 1);
    rowmap[off + pos] = p;
  }
}

// ---------------- grouped GEMM (R2 structure; ct-fast XCD swizzle) ---------
// MODE 0: A = gathered hs bf16, B = w1t [E][I][H] bf16, C = silu -> act bf16
// MODE 1: A = act bf16, B = w2t [E][H][I] bf16, C -> atomicAdd out * wgt
template <int MODE, int NCT>
__launch_bounds__(256, 3)
__global__ void moe_gemm(const unsigned short* __restrict__ hsb,
                         const unsigned short* __restrict__ wt,
                         const unsigned short* __restrict__ act_in,
                         unsigned short* __restrict__ act_out,
                         float* __restrict__ out,
                         const int* __restrict__ counts,
                         const int* __restrict__ rowmap,
                         const float* __restrict__ wgt) {
  constexpr int KD = (MODE == 0) ? H_DIM : I_DIM;
  constexpr int NWG = MAX_RT * NCT;    // %8 == 0 for both modes

  __shared__ unsigned short As[BM * BK];
  __shared__ unsigned short Bs[BN * BK];
  __shared__ int s_pair[BM];
  __shared__ float s_w[BM];

  // T1 bijective XCD swizzle, ct FAST within chunk: A-tile stays L2-resident
  const int bid = blockIdx.x;
  const int wgid = (bid & 7) * (NWG / 8) + (bid >> 3);
  const int rt = wgid / NCT;
  const int ct = wgid % NCT;

  // expert walk from counts (prefix on the fly)
  int e = -1, loc_rt = 0, off_e = 0, cnt = 0;
  {
    int acc_t = 0, off = 0;
#pragma unroll
    for (int ee = 0; ee < E_NUM; ++ee) {
      const int c = counts[ee];
      const int nt = (c + BM - 1) >> 7;
      if (e < 0 && rt < acc_t + nt) { e = ee; loc_rt = rt - acc_t; off_e = off; cnt = c; }
      acc_t += nt; off += c;
    }
  }
  if (e < 0) return;

  const int cnt_local = min(BM, cnt - loc_rt * BM);
  const int r_base = off_e + loc_rt * BM;
  const int th = threadIdx.x;
  const int lane = th & 63, wid = th >> 6;

  if (MODE == 1 && th < BM) {
    int r = loc_rt * BM + th;
    if (r >= cnt) r = cnt - 1;
    const int p = rowmap[off_e + r];
    s_pair[th] = p;
    s_w[th] = wgt[p];
  }

  const int n0 = ct * BN;
  const unsigned short* wbase = wt + (size_t)e * ((size_t)I_DIM * H_DIM) + (size_t)n0 * KD;

  // staging geometry: lane covers (row = i*32 + wid*8 + lane/8, chunk = lane%8)
  // LDS dest linear; source chunk pre-swizzled: cg = (lane&7) ^ (row&7)
  const int srow = lane >> 3;
  const int cg = (lane & 7) ^ srow;
  const char* aptr[4];
  const char* bptr[4];
#pragma unroll
  for (int i = 0; i < 4; ++i) {
    const int r = i * 32 + wid * 8 + srow;
    const int rr = (r < cnt_local) ? r : (cnt_local - 1);
    if (MODE == 0) {
      const int tok = rowmap[off_e + loc_rt * BM + rr] >> 1;
      aptr[i] = (const char*)(hsb + (size_t)tok * H_DIM) + cg * 16;
    } else {
      aptr[i] = (const char*)(act_in + (size_t)(r_base + rr) * I_DIM) + cg * 16;
    }
    bptr[i] = (const char*)(wbase + (size_t)r * KD) + cg * 16;
  }
  unsigned short* dstA[4];
  unsigned short* dstB[4];
#pragma unroll
  for (int i = 0; i < 4; ++i) {
    dstA[i] = &As[(i * 32 + wid * 8) * BK];   // wave-uniform
    dstB[i] = &Bs[(i * 32 + wid * 8) * BK];
  }

  f32x4 acc[4][4];
#pragma unroll
  for (int m = 0; m < 4; ++m)
#pragma unroll
    for (int n = 0; n < 4; ++n) acc[m][n] = (f32x4){0.f, 0.f, 0.f, 0.f};

  const int wm = (wid >> 1) * 64;
  const int wn = (wid & 1) * 64;
  const int fr = lane & 15;
  const int fq = lane >> 4;
  const int sxor = fr & 7;

  for (int k0 = 0; k0 < KD; k0 += BK) {
    const int kb = k0 * 2;
#pragma unroll
    for (int i = 0; i < 4; ++i) gload16(aptr[i] + kb, dstA[i]);
#pragma unroll
    for (int i = 0; i < 4; ++i) gload16(bptr[i] + kb, dstB[i]);
    __syncthreads();   // compiler drains vmcnt before s_barrier

#pragma unroll
    for (int kk = 0; kk < 2; ++kk) {
      bf16x8 af[4], bf[4];
#pragma unroll
      for (int m = 0; m < 4; ++m)
        af[m] = *reinterpret_cast<const bf16x8*>(
            &As[(wm + m * 16 + fr) * BK + ((kk * 4 + fq) ^ sxor) * 8]);
#pragma unroll
      for (int n = 0; n < 4; ++n)
        bf[n] = *reinterpret_cast<const bf16x8*>(
            &Bs[(wn + n * 16 + fr) * BK + ((kk * 4 + fq) ^ sxor) * 8]);
#pragma unroll
      for (int m = 0; m < 4; ++m)
#pragma unroll
        for (int n = 0; n < 4; ++n)
          acc[m][n] = __builtin_amdgcn_mfma_f32_16x16x32_bf16(af[m], bf[n], acc[m][n], 0, 0, 0);
    }
    __syncthreads();
  }

  // ---- epilogue ----
#pragma unroll
  for (int m = 0; m < 4; ++m) {
    const int row = wm + m * 16 + fq * 4;
#pragma unroll
    for (int n = 0; n < 4; ++n) {
      const int col = wn + n * 16 + fr;
#pragma unroll
      for (int r = 0; r < 4; ++r) {
        const int rw = row + r;
        if (rw < cnt_local) {
          const float x = acc[m][n][r];
          if (MODE == 0) {
            const float s = x / (1.f + __expf(-x));   // silu
            act_out[(size_t)(r_base + rw) * I_DIM + n0 + col] = f2bf(s);
          } else {
            const int p = s_pair[rw];
            const int tok = p >> 1;
            atomicAdd(out + (size_t)tok * H_DIM + n0 + col, x * s_w[rw]);
          }
        }
      }
    }
  }
}

// ---------------- launch ----------------
extern "C" void kernel_launch(void* const* d_in, const int* in_sizes, int n_in,
                              void* d_out, int out_size, void* d_ws, size_t ws_size,
                              hipStream_t stream) {
  const float* hs = (const float*)d_in[0];
  const float* gw = (const float*)d_in[1];
  const float* w1 = (const float*)d_in[2];
  const float* w2 = (const float*)d_in[3];
  float* out = (float*)d_out;

  char* ws = (char*)d_ws;
  const size_t WMAT = (size_t)E_NUM * I_DIM * H_DIM * 2;   // 58,720,256 B
  unsigned short* w1t = (unsigned short*)ws;                // [E][I][H] bf16
  unsigned short* w2t = (unsigned short*)(ws + WMAT);       // [E][H][I] bf16
  unsigned short* act = (unsigned short*)(ws + 2 * WMAT);   // [NPAIR][I] bf16
  unsigned short* hsb = (unsigned short*)(ws + 3 * WMAT);   // [T][H] bf16
  char* small = ws + 3 * WMAT + (size_t)T_TOK * H_DIM * 2;
  int* eid = (int*)small;                          // NPAIR
  float* wgt = (float*)(small + NPAIR * 4);        // NPAIR
  int* rowmap = (int*)(small + 2 * NPAIR * 4);     // NPAIR
  int* counts = (int*)(small + 3 * NPAIR * 4);     // 8
  int* fill = counts + 8;                          // 8

  hipMemsetAsync(d_out, 0, (size_t)T_TOK * H_DIM * sizeof(float), stream);
  hipMemsetAsync(counts, 0, 16 * sizeof(int), stream);

  transpose_cvt<<<dim3(I_DIM / 64, H_DIM / 64, E_NUM), 256, 0, stream>>>(w1, w1t, H_DIM, I_DIM);
  transpose_cvt<<<dim3(H_DIM / 64, I_DIM / 64, E_NUM), 256, 0, stream>>>(w2, w2t, I_DIM, H_DIM);

  router_kernel<<<T_TOK / 4, 256, 0, stream>>>(hs, gw, hsb, eid, wgt, counts);
  scatter_kernel<<<NPAIR / 256, 256, 0, stream>>>(eid, counts, fill, rowmap);

  moe_gemm<0, I_DIM / BN><<<MAX_RT * (I_DIM / BN), 256, 0, stream>>>(
      hsb, w1t, nullptr, act, nullptr, counts, rowmap, wgt);
  moe_gemm<1, H_DIM / BN><<<MAX_RT * (H_DIM / BN), 256, 0, stream>>>(
      hsb, w2t, act, nullptr, out, counts, rowmap, wgt);
}

// Round 6
// 286.444 us; speedup vs baseline: 1.6378x; 1.3484x over previous
//
#include <hip/hip_runtime.h>
#include <hip/hip_bf16.h>

// ---------------- problem constants (match setup_inputs) ----------------
#define T_TOK 4096
#define H_DIM 1024
#define E_NUM 8
#define I_DIM 3584
#define NPAIR (T_TOK * 2)   // top_k = 2
#define MAX_RT 72           // worst-case total row tiles: sum ceil(cnt_e/128) <= 64+7

#define BM 128
#define BN 128
#define BK 64

typedef __attribute__((ext_vector_type(8))) short bf16x8;
typedef __attribute__((ext_vector_type(4))) float f32x4;
typedef __attribute__((ext_vector_type(8))) unsigned short ushort8_t;
typedef __attribute__((ext_vector_type(4))) unsigned short ushort4_t;

// RNE fp32 -> bf16
__device__ __forceinline__ unsigned short f2bf(float x) {
  unsigned int u = __float_as_uint(x);
  unsigned int r = (u + 0x7FFFu + ((u >> 16) & 1u)) >> 16;
  return (unsigned short)r;
}

// async 16B global -> LDS (dest: wave-uniform base, HW adds lane*16)
__device__ __forceinline__ void gload16(const void* g, unsigned short* l) {
  __builtin_amdgcn_global_load_lds(
      (const __attribute__((address_space(1))) void*)g,
      (__attribute__((address_space(3))) void*)l, 16, 0, 0);
}

// ---------------- transpose + fp32->bf16 convert ----------------
// src: [E][R][C] fp32 -> dst: [E][C][R] bf16.  grid (C/64, R/64, E), 256 thr
__global__ void transpose_cvt(const float* __restrict__ src,
                              unsigned short* __restrict__ dst, int R, int C) {
  __shared__ float tile[64][65];   // stride 65 -> 2-way max on column reads
  const int e = blockIdx.z;
  const int c0 = blockIdx.x * 64, r0 = blockIdx.y * 64;
  const float* s = src + (size_t)e * R * C;
  unsigned short* d = dst + (size_t)e * R * C;
  const int th = threadIdx.x;
  const int tr = th >> 4;          // 0..15
  const int tc4 = (th & 15) * 4;   // 0..60
#pragma unroll
  for (int it = 0; it < 4; ++it) {
    const int r = it * 16 + tr;
    float4 v = *reinterpret_cast<const float4*>(s + (size_t)(r0 + r) * C + c0 + tc4);
    tile[r][tc4] = v.x; tile[r][tc4 + 1] = v.y; tile[r][tc4 + 2] = v.z; tile[r][tc4 + 3] = v.w;
  }
  __syncthreads();
  const int wc = th >> 3;          // 0..31
  const int wr = (th & 7) * 8;     // 0..56
#pragma unroll
  for (int it = 0; it < 2; ++it) {
    const int c = it * 32 + wc;
    ushort8_t o;
#pragma unroll
    for (int j = 0; j < 8; ++j) o[j] = f2bf(tile[wr + j][c]);
    *reinterpret_cast<ushort8_t*>(d + (size_t)(c0 + c) * R + r0 + wr) = o;
  }
}

// ---------------- router: LDS-staged gw, float4 hs, LDS-aggregated counts --
// block = 256 threads (4 waves), 16 tokens/block; grid = T/16 = 256
__global__ void router_kernel(const float* __restrict__ hs, const float* __restrict__ gw,
                              unsigned short* __restrict__ hsb,
                              int* __restrict__ eid, float* __restrict__ wgt,
                              int* __restrict__ counts) {
  __shared__ float s_gw[8192];   // gw as 2048 float4 units, XOR-swizzled
  __shared__ int s_cnt[E_NUM];
  const int th = threadIdx.x;
  // stage gw: unit u (16B) at phys u ^ ((u>>3)&7)  (bijective involution)
  for (int u = th; u < 2048; u += 256) {
    const f32x4 v = *reinterpret_cast<const f32x4*>(gw + u * 4);
    *reinterpret_cast<f32x4*>(&s_gw[(u ^ ((u >> 3) & 7)) * 4]) = v;
  }
  if (th < E_NUM) s_cnt[th] = 0;
  __syncthreads();

  const int l = th & 63, w = th >> 6;
#pragma unroll 1
  for (int tt = 0; tt < 4; ++tt) {
    const int t = blockIdx.x * 16 + w * 4 + tt;
    const float* hrow = hs + (size_t)t * H_DIM;
    unsigned short* brow = hsb + (size_t)t * H_DIM;
    float acc[E_NUM];
#pragma unroll
    for (int e = 0; e < E_NUM; ++e) acc[e] = 0.f;
#pragma unroll
    for (int i = 0; i < 4; ++i) {
      const int h0 = i * 256 + l * 4;
      const f32x4 x = *reinterpret_cast<const f32x4*>(hrow + h0);
      ushort4_t o = { f2bf(x[0]), f2bf(x[1]), f2bf(x[2]), f2bf(x[3]) };
      *reinterpret_cast<ushort4_t*>(brow + h0) = o;
#pragma unroll
      for (int j = 0; j < 4; ++j) {
        const int h = h0 + j;
        const int p0 = (h * 2) ^ ((h >> 2) & 7);   // lanes spread all 8 bank-groups
        const f32x4 g0 = *reinterpret_cast<const f32x4*>(&s_gw[p0 * 4]);
        const f32x4 g1 = *reinterpret_cast<const f32x4*>(&s_gw[(p0 ^ 1) * 4]);
        acc[0] += x[j] * g0[0]; acc[1] += x[j] * g0[1];
        acc[2] += x[j] * g0[2]; acc[3] += x[j] * g0[3];
        acc[4] += x[j] * g1[0]; acc[5] += x[j] * g1[1];
        acc[6] += x[j] * g1[2]; acc[7] += x[j] * g1[3];
      }
    }
#pragma unroll
    for (int e = 0; e < E_NUM; ++e) {
#pragma unroll
      for (int off = 1; off < 64; off <<= 1) acc[e] += __shfl_xor(acc[e], off);
    }
    if (l == 0) {
      int i1 = 0;
#pragma unroll
      for (int e = 1; e < E_NUM; ++e) if (acc[e] > acc[i1]) i1 = e;
      int i2 = (i1 == 0) ? 1 : 0;
#pragma unroll
      for (int e = 0; e < E_NUM; ++e) if (e != i1 && acc[e] > acc[i2]) i2 = e;
      const float e2 = __expf(acc[i2] - acc[i1]);
      const float inv = 1.f / (1.f + e2);
      eid[t * 2] = i1;     wgt[t * 2] = inv;
      eid[t * 2 + 1] = i2; wgt[t * 2 + 1] = e2 * inv;
      atomicAdd(&s_cnt[i1], 1);
      atomicAdd(&s_cnt[i2], 1);
    }
  }
  __syncthreads();
  if (th < E_NUM && s_cnt[th] > 0) atomicAdd(&counts[th], s_cnt[th]);
}

// ---------------- scatter: block-local histogram + range reservation -------
// grid = NPAIR/256 = 32 blocks; <=8 global atomics per block
__global__ void scatter_kernel(const int* __restrict__ eid, const int* __restrict__ counts,
                               int* __restrict__ fill, int* __restrict__ rowmap) {
  __shared__ int hist[E_NUM], base[E_NUM];
  const int th = threadIdx.x;
  const int p = blockIdx.x * 256 + th;
  if (th < E_NUM) hist[th] = 0;
  __syncthreads();
  const int e = eid[p];
  const int rloc = atomicAdd(&hist[e], 1);   // local rank (LDS atomic)
  __syncthreads();
  if (th < E_NUM) base[th] = (hist[th] > 0) ? atomicAdd(&fill[th], hist[th]) : 0;
  __syncthreads();
  int off = 0;
#pragma unroll
  for (int i = 0; i < E_NUM; ++i) off += (i < e) ? counts[i] : 0;
  rowmap[off + base[e] + rloc] = p;
}

// ---------------- grouped GEMM (R2 structure; ct-fast XCD swizzle) ---------
// MODE 0: A = gathered hs bf16, B = w1t [E][I][H] bf16, C = silu -> act bf16
// MODE 1: A = act bf16, B = w2t [E][H][I] bf16, C -> atomicAdd out * wgt
template <int MODE, int NCT>
__launch_bounds__(256, 3)
__global__ void moe_gemm(const unsigned short* __restrict__ hsb,
                         const unsigned short* __restrict__ wt,
                         const unsigned short* __restrict__ act_in,
                         unsigned short* __restrict__ act_out,
                         float* __restrict__ out,
                         const int* __restrict__ counts,
                         const int* __restrict__ rowmap,
                         const float* __restrict__ wgt) {
  constexpr int KD = (MODE == 0) ? H_DIM : I_DIM;
  constexpr int NWG = MAX_RT * NCT;    // %8 == 0 for both modes

  __shared__ unsigned short As[BM * BK];
  __shared__ unsigned short Bs[BN * BK];
  __shared__ int s_pair[BM];
  __shared__ float s_w[BM];

  // T1 bijective XCD swizzle, ct FAST within chunk: A-tile stays L2-resident
  const int bid = blockIdx.x;
  const int wgid = (bid & 7) * (NWG / 8) + (bid >> 3);
  const int rt = wgid / NCT;
  const int ct = wgid % NCT;

  // expert walk from counts (prefix on the fly)
  int e = -1, loc_rt = 0, off_e = 0, cnt = 0;
  {
    int acc_t = 0, off = 0;
#pragma unroll
    for (int ee = 0; ee < E_NUM; ++ee) {
      const int c = counts[ee];
      const int nt = (c + BM - 1) >> 7;
      if (e < 0 && rt < acc_t + nt) { e = ee; loc_rt = rt - acc_t; off_e = off; cnt = c; }
      acc_t += nt; off += c;
    }
  }
  if (e < 0) return;

  const int cnt_local = min(BM, cnt - loc_rt * BM);
  const int r_base = off_e + loc_rt * BM;
  const int th = threadIdx.x;
  const int lane = th & 63, wid = th >> 6;

  if (MODE == 1 && th < BM) {
    int r = loc_rt * BM + th;
    if (r >= cnt) r = cnt - 1;
    const int p = rowmap[off_e + r];
    s_pair[th] = p;
    s_w[th] = wgt[p];
  }

  const int n0 = ct * BN;
  const unsigned short* wbase = wt + (size_t)e * ((size_t)I_DIM * H_DIM) + (size_t)n0 * KD;

  // staging geometry: lane covers (row = i*32 + wid*8 + lane/8, chunk = lane%8)
  // LDS dest linear; source chunk pre-swizzled: cg = (lane&7) ^ (row&7)
  const int srow = lane >> 3;
  const int cg = (lane & 7) ^ srow;
  const char* aptr[4];
  const char* bptr[4];
#pragma unroll
  for (int i = 0; i < 4; ++i) {
    const int r = i * 32 + wid * 8 + srow;
    const int rr = (r < cnt_local) ? r : (cnt_local - 1);
    if (MODE == 0) {
      const int tok = rowmap[off_e + loc_rt * BM + rr] >> 1;
      aptr[i] = (const char*)(hsb + (size_t)tok * H_DIM) + cg * 16;
    } else {
      aptr[i] = (const char*)(act_in + (size_t)(r_base + rr) * I_DIM) + cg * 16;
    }
    bptr[i] = (const char*)(wbase + (size_t)r * KD) + cg * 16;
  }
  unsigned short* dstA[4];
  unsigned short* dstB[4];
#pragma unroll
  for (int i = 0; i < 4; ++i) {
    dstA[i] = &As[(i * 32 + wid * 8) * BK];   // wave-uniform
    dstB[i] = &Bs[(i * 32 + wid * 8) * BK];
  }

  f32x4 acc[4][4];
#pragma unroll
  for (int m = 0; m < 4; ++m)
#pragma unroll
    for (int n = 0; n < 4; ++n) acc[m][n] = (f32x4){0.f, 0.f, 0.f, 0.f};

  const int wm = (wid >> 1) * 64;
  const int wn = (wid & 1) * 64;
  const int fr = lane & 15;
  const int fq = lane >> 4;
  const int sxor = fr & 7;

  for (int k0 = 0; k0 < KD; k0 += BK) {
    const int kb = k0 * 2;
#pragma unroll
    for (int i = 0; i < 4; ++i) gload16(aptr[i] + kb, dstA[i]);
#pragma unroll
    for (int i = 0; i < 4; ++i) gload16(bptr[i] + kb, dstB[i]);
    __syncthreads();   // compiler drains vmcnt before s_barrier

#pragma unroll
    for (int kk = 0; kk < 2; ++kk) {
      bf16x8 af[4], bf[4];
#pragma unroll
      for (int m = 0; m < 4; ++m)
        af[m] = *reinterpret_cast<const bf16x8*>(
            &As[(wm + m * 16 + fr) * BK + ((kk * 4 + fq) ^ sxor) * 8]);
#pragma unroll
      for (int n = 0; n < 4; ++n)
        bf[n] = *reinterpret_cast<const bf16x8*>(
            &Bs[(wn + n * 16 + fr) * BK + ((kk * 4 + fq) ^ sxor) * 8]);
#pragma unroll
      for (int m = 0; m < 4; ++m)
#pragma unroll
        for (int n = 0; n < 4; ++n)
          acc[m][n] = __builtin_amdgcn_mfma_f32_16x16x32_bf16(af[m], bf[n], acc[m][n], 0, 0, 0);
    }
    __syncthreads();
  }

  // ---- epilogue ----
#pragma unroll
  for (int m = 0; m < 4; ++m) {
    const int row = wm + m * 16 + fq * 4;
#pragma unroll
    for (int n = 0; n < 4; ++n) {
      const int col = wn + n * 16 + fr;
#pragma unroll
      for (int r = 0; r < 4; ++r) {
        const int rw = row + r;
        if (rw < cnt_local) {
          const float x = acc[m][n][r];
          if (MODE == 0) {
            const float s = x / (1.f + __expf(-x));   // silu
            act_out[(size_t)(r_base + rw) * I_DIM + n0 + col] = f2bf(s);
          } else {
            const int p = s_pair[rw];
            const int tok = p >> 1;
            atomicAdd(out + (size_t)tok * H_DIM + n0 + col, x * s_w[rw]);
          }
        }
      }
    }
  }
}

// ---------------- launch ----------------
extern "C" void kernel_launch(void* const* d_in, const int* in_sizes, int n_in,
                              void* d_out, int out_size, void* d_ws, size_t ws_size,
                              hipStream_t stream) {
  const float* hs = (const float*)d_in[0];
  const float* gw = (const float*)d_in[1];
  const float* w1 = (const float*)d_in[2];
  const float* w2 = (const float*)d_in[3];
  float* out = (float*)d_out;

  char* ws = (char*)d_ws;
  const size_t WMAT = (size_t)E_NUM * I_DIM * H_DIM * 2;   // 58,720,256 B
  unsigned short* w1t = (unsigned short*)ws;                // [E][I][H] bf16
  unsigned short* w2t = (unsigned short*)(ws + WMAT);       // [E][H][I] bf16
  unsigned short* act = (unsigned short*)(ws + 2 * WMAT);   // [NPAIR][I] bf16
  unsigned short* hsb = (unsigned short*)(ws + 3 * WMAT);   // [T][H] bf16
  char* small = ws + 3 * WMAT + (size_t)T_TOK * H_DIM * 2;
  int* eid = (int*)small;                          // NPAIR
  float* wgt = (float*)(small + NPAIR * 4);        // NPAIR
  int* rowmap = (int*)(small + 2 * NPAIR * 4);     // NPAIR
  int* counts = (int*)(small + 3 * NPAIR * 4);     // 8
  int* fill = counts + 8;                          // 8

  hipMemsetAsync(d_out, 0, (size_t)T_TOK * H_DIM * sizeof(float), stream);
  hipMemsetAsync(counts, 0, 16 * sizeof(int), stream);

  transpose_cvt<<<dim3(I_DIM / 64, H_DIM / 64, E_NUM), 256, 0, stream>>>(w1, w1t, H_DIM, I_DIM);
  transpose_cvt<<<dim3(H_DIM / 64, I_DIM / 64, E_NUM), 256, 0, stream>>>(w2, w2t, I_DIM, H_DIM);

  router_kernel<<<T_TOK / 16, 256, 0, stream>>>(hs, gw, hsb, eid, wgt, counts);
  scatter_kernel<<<NPAIR / 256, 256, 0, stream>>>(eid, counts, fill, rowmap);

  moe_gemm<0, I_DIM / BN><<<MAX_RT * (I_DIM / BN), 256, 0, stream>>>(
      hsb, w1t, nullptr, act, nullptr, counts, rowmap, wgt);
  moe_gemm<1, H_DIM / BN><<<MAX_RT * (H_DIM / BN), 256, 0, stream>>>(
      hsb, w2t, act, nullptr, out, counts, rowmap, wgt);
}